// Round 8
// baseline (280.204 us; speedup 1.0000x reference)
//
#include <hip/hip_runtime.h>

#define M_DIM 2048
#define K_DIM 4096
#define N_DIM 4096
#define KTILES (K_DIM / 64)

typedef unsigned short u16;
typedef unsigned int u32;
typedef __bf16 bf16x8 __attribute__((ext_vector_type(8)));
typedef float f32x4 __attribute__((ext_vector_type(4)));
typedef float f4 __attribute__((ext_vector_type(4)));
typedef u16 u16x8 __attribute__((ext_vector_type(8)));
typedef u32 u32x4 __attribute__((ext_vector_type(4)));

// fp32 -> bf16 round-to-nearest-even
__device__ __forceinline__ u16 f2bf(float f) {
    unsigned int u = __float_as_uint(f);
    u += 0x7fffu + ((u >> 16) & 1u);
    return (u16)(u >> 16);
}

// pack two fp32 -> (bf16(lo) | bf16(hi)<<16), RNE
__device__ __forceinline__ u32 pack2(float lo, float hi) {
    u32 a = __float_as_uint(lo); a += 0x7fffu + ((a >> 16) & 1u);
    u32 b = __float_as_uint(hi); b += 0x7fffu + ((b >> 16) & 1u);
    return (a >> 16) | (b & 0xffff0000u);
}

// async global->LDS, 16B per lane. LDS dest must be wave-uniform base + lane*16.
__device__ __forceinline__ void load16(const void* g, void* l) {
    __builtin_amdgcn_global_load_lds(
        (__attribute__((address_space(1))) const void*)g,
        (__attribute__((address_space(3))) void*)l,
        16, 0, 0);
}

// ------- prep_t: LDS-free transpose, Bt[n][k] = bf16((mask?W:0)[k][n]) ------
__global__ __launch_bounds__(256) void prep_t(const float* __restrict__ W,
                                              const float* __restrict__ Msk,
                                              u16* __restrict__ Bt) {
    const int t = threadIdx.x;
    const int n0 = (blockIdx.x & 31) * 128;         // 32 n-tiles of 128
    const int k0 = (blockIdx.x >> 5) * 64;          // 64 k-tiles of 64
    const int ko = t & 7;                           // k-octet within tile
    const int ng = t >> 3;                          // n-group (4 cols), 0..31

    const float* Wp = W   + (size_t)(k0 + 8 * ko) * N_DIM + n0 + 4 * ng;
    const float* Mp = Msk + (size_t)(k0 + 8 * ko) * N_DIM + n0 + 4 * ng;

    f4 a[8];
#pragma unroll
    for (int j = 0; j < 8; ++j) {
        f4 wv = *(const f4*)(Wp + (size_t)j * N_DIM);
        f4 mv = *(const f4*)(Mp + (size_t)j * N_DIM);
        a[j][0] = mv[0] != 0.f ? wv[0] : 0.f;
        a[j][1] = mv[1] != 0.f ? wv[1] : 0.f;
        a[j][2] = mv[2] != 0.f ? wv[2] : 0.f;
        a[j][3] = mv[3] != 0.f ? wv[3] : 0.f;
    }

    u16* bp = Bt + (size_t)(n0 + 4 * ng) * K_DIM + k0 + 8 * ko;
#pragma unroll
    for (int i = 0; i < 4; ++i) {                   // n within the float4
        u32x4 o;
        o[0] = pack2(a[0][i], a[1][i]);
        o[1] = pack2(a[2][i], a[3][i]);
        o[2] = pack2(a[4][i], a[5][i]);
        o[3] = pack2(a[6][i], a[7][i]);
        *(u32x4*)(bp + (size_t)i * K_DIM) = o;
    }
}

// ------------------- prep_x: x f32 -> bf16, 16 floats/thread ----------------
__global__ __launch_bounds__(256) void prep_x(const float* __restrict__ x,
                                              u16* __restrict__ xb) {
    const int t = threadIdx.x;
    size_t i = ((size_t)blockIdx.x * 256 + t) * 16;
#pragma unroll
    for (int h = 0; h < 2; ++h) {
        f4 v0 = *(const f4*)(x + i + h * 8);
        f4 v1 = *(const f4*)(x + i + h * 8 + 4);
        u16x8 o;
        o[0] = f2bf(v0[0]); o[1] = f2bf(v0[1]); o[2] = f2bf(v0[2]); o[3] = f2bf(v0[3]);
        o[4] = f2bf(v1[0]); o[5] = f2bf(v1[1]); o[6] = f2bf(v1[2]); o[7] = f2bf(v1[3]);
        *(u16x8*)(xb + i + h * 8) = o;
    }
}

// --- gemm8: 128m x 256n, 2m x 2n x 2k waves, A-from-global + B-in-LDS -------
// R6 skeleton (end-of-iter counted wait + barrier, never drains; XCD swizzle;
// cross-k LDS reduce epilogue), with A REMOVED FROM LDS: fA fragments are 16
// contiguous bytes/lane of xb (L3-resident), loaded to registers one full
// K-tile ahead. LDS traffic/K-tile drops 96+48 KB -> 64+32 KB, putting the
// MFMA pipe (not LDS) on the critical path for the first time.
// Per iteration (per-thread vm queue in brackets, oldest first):
//   [8 ds_read B from bC]  [gload fA(kt+1) x4]
//   vmcnt(4)   <- queue {fA(kt) 4, SB(kt+1) 4, fA(kt+1) 4}: certifies fA(kt)
//                 and SB(kt+1); fA(kt+1) stays in flight. Never drains.
//   s_barrier  <- collective: every wave certified its SB(kt+1) writes, and
//                 every wave's reads of buf (kt-1)%3 were lgkm(0)-certified
//                 before this barrier => SB below is write-after-read safe.
//   [4 SB(kt+2) into bN2]
//   lgkm(4) -> 16 MFMA (fA x fB0) -> lgkm(0) -> 16 MFMA (fA x fB1)
// fA double-buffer via 2x unroll (no runtime indexing). sched_barrier(0)
// after every inline-asm wait (rule #18). Numerics identical to R6.
__global__ __launch_bounds__(512, 2) void gemm8(const u16* __restrict__ A,   // M x K bf16
                                                const u16* __restrict__ Bt,  // N x K bf16
                                                const float* __restrict__ bias,
                                                float* __restrict__ C) {
    __shared__ __align__(16) u16 Bs[4][256 * 64];   // 3 rotating + 1 epilogue scratch

    const int t = threadIdx.x;
    // XCD-aware decode: XCD x owns an 8(bm) x 4(bn) chunk
    const int wgid = blockIdx.x;        // 256 WGs, wgid%8 == XCD [m09]
    const int xcd = wgid & 7, c = wgid >> 3;
    const int bm = (xcd & 1) * 8 + (c & 7);     // M/128 = 16
    const int bn = (xcd >> 1) * 4 + (c >> 3);   // N/256 = 16

    const int srow   = t >> 3;
    const int schunk = (t & 7) ^ (srow & 7);
    const u16* gB = Bt + (size_t)(bn * 256 + srow) * K_DIM + schunk * 8;

    const int lane = t & 63;
    const int wv   = t >> 6;
    const int kh = wv >> 2;             // k-half of every K-tile (0/1)
    const int wq = wv & 3;              // position in 2m x 2n wave grid
    const int mo = (wq >> 1) * 64;      // wave m-origin (0/64)
    const int no = (wq & 1) * 128;      // wave n-origin (0/128)
    const int fr = lane & 15;
    const int q  = lane >> 4;
    const int sw = fr & 7;
    const int colK = (((kh << 2) + q) ^ sw) * 8;

    // per-lane global base for A fragments: row bm*128+mo+fr, k = kh*32+q*8
    const u16* gAf = A + (size_t)(bm * 128 + mo + fr) * K_DIM + kh * 32 + q * 8;

#define SB(buf, kt, j) load16(gB + (size_t)(kt) * 64 + (size_t)(j) * 64 * K_DIM, \
                              (buf) + (j) * 4096 + t * 8)
#define LDA(dst, kt) do { \
    _Pragma("unroll") \
    for (int i_ = 0; i_ < 4; ++i_) \
        dst[i_] = *(const bf16x8*)(gAf + (size_t)(i_ * 16) * K_DIM + (size_t)(kt) * 64); \
    } while (0)

#define BODY(kt, fAc, fAn) do { \
    const int kn_ = ((kt) + 2) & (KTILES - 1); \
    bf16x8 fB0[4], fB1[4]; \
    _Pragma("unroll") \
    for (int j_ = 0; j_ < 4; ++j_) \
        fB0[j_] = *(const bf16x8*)(bC + (no + j_ * 16 + fr) * 64 + colK); \
    _Pragma("unroll") \
    for (int j_ = 0; j_ < 4; ++j_) \
        fB1[j_] = *(const bf16x8*)(bC + (no + 64 + j_ * 16 + fr) * 64 + colK); \
    LDA(fAn, ((kt) + 1) & (KTILES - 1)); \
    asm volatile("s_waitcnt vmcnt(4)" ::: "memory"); \
    __builtin_amdgcn_sched_barrier(0); \
    __builtin_amdgcn_s_barrier(); \
    SB(bN2, kn_, 0); SB(bN2, kn_, 1); SB(bN2, kn_, 2); SB(bN2, kn_, 3); \
    asm volatile("s_waitcnt lgkmcnt(4)" ::: "memory"); \
    __builtin_amdgcn_sched_barrier(0); \
    __builtin_amdgcn_s_setprio(1); \
    _Pragma("unroll") \
    for (int i_ = 0; i_ < 4; ++i_) \
        _Pragma("unroll") \
        for (int j_ = 0; j_ < 4; ++j_) \
            acc[i_][j_] = __builtin_amdgcn_mfma_f32_16x16x32_bf16( \
                fAc[i_], fB0[j_], acc[i_][j_], 0, 0, 0); \
    __builtin_amdgcn_s_setprio(0); \
    asm volatile("s_waitcnt lgkmcnt(0)" ::: "memory"); \
    __builtin_amdgcn_sched_barrier(0); \
    __builtin_amdgcn_s_setprio(1); \
    _Pragma("unroll") \
    for (int i_ = 0; i_ < 4; ++i_) \
        _Pragma("unroll") \
        for (int j_ = 0; j_ < 4; ++j_) \
            acc[i_][j_ + 4] = __builtin_amdgcn_mfma_f32_16x16x32_bf16( \
                fAc[i_], fB1[j_], acc[i_][j_ + 4], 0, 0, 0); \
    __builtin_amdgcn_s_setprio(0); \
    u16* tmp_ = bC; bC = bN1; bN1 = bN2; bN2 = tmp_; \
    } while (0)

    f32x4 acc[4][8] = {};   // [i: m 4x16][j: n 8x16]
    bf16x8 fA_a[4], fA_b[4];

    // rotating B buffer pointers (register-held; never runtime-indexed)
    u16 *bC = (u16*)Bs[0], *bN1 = (u16*)Bs[1], *bN2 = (u16*)Bs[2];

    // prologue. vm queue after issue: SB0(4), fA0(4), SB1(4) = 12.
    // vmcnt(8) certifies SB0 (tile 0 readable); fA0+SB1 stay in flight.
    SB(bC, 0, 0);  SB(bC, 0, 1);  SB(bC, 0, 2);  SB(bC, 0, 3);
    LDA(fA_a, 0);
    SB(bN1, 1, 0); SB(bN1, 1, 1); SB(bN1, 1, 2); SB(bN1, 1, 3);
    asm volatile("s_waitcnt vmcnt(8)" ::: "memory");
    __builtin_amdgcn_sched_barrier(0);
    __builtin_amdgcn_s_barrier();

    for (int kt = 0; kt < KTILES; kt += 2) {
        BODY(kt,     fA_a, fA_b);
        BODY(kt + 1, fA_b, fA_a);
    }

    // ---- epilogue: cross-k-half reduction through LDS ----------------------
    asm volatile("s_waitcnt vmcnt(0)" ::: "memory");
    __builtin_amdgcn_s_barrier();

    // 32 KB scratch region per wq: Bs[0..3]
    float* red = (float*)Bs[0] + (size_t)wq * (256 * 64 / 2);

    if (kh == 1) {
#pragma unroll
        for (int i = 0; i < 4; ++i)
#pragma unroll
            for (int j = 0; j < 8; ++j)
                *(f32x4*)(red + (i * 8 + j) * 256 + lane * 4) = acc[i][j];
    }
    asm volatile("s_waitcnt lgkmcnt(0)" ::: "memory");
    __builtin_amdgcn_s_barrier();

    if (kh == 0) {
        const int rb = q * 4;
#pragma unroll
        for (int i = 0; i < 4; ++i) {
#pragma unroll
            for (int j = 0; j < 8; ++j) {
                f32x4 other = *(const f32x4*)(red + (i * 8 + j) * 256 + lane * 4);
                int n = bn * 256 + no + j * 16 + fr;
                float bv = bias[n];
#pragma unroll
                for (int r = 0; r < 4; ++r) {
                    int m = bm * 128 + mo + i * 16 + rb + r;
                    C[(size_t)m * N_DIM + n] = acc[i][j][r] + other[r] + bv;
                }
            }
        }
    }
#undef SB
#undef LDA
#undef BODY
}

extern "C" void kernel_launch(void* const* d_in, const int* in_sizes, int n_in,
                              void* d_out, int out_size, void* d_ws, size_t ws_size,
                              hipStream_t stream) {
    const float* x    = (const float*)d_in[0];  // 2048 x 4096
    const float* mask = (const float*)d_in[1];  // 4096 x 4096
    const float* W    = (const float*)d_in[2];  // 4096 x 4096
    const float* bias = (const float*)d_in[3];  // 4096
    float* out = (float*)d_out;                 // 2048 x 4096

    u16* Bt = (u16*)d_ws;                                   // N*K bf16 = 32 MB
    u16* xb = (u16*)d_ws + (size_t)N_DIM * K_DIM;           // M*K bf16 = 16 MB

    prep_t<<<2048, 256, 0, stream>>>(W, mask, Bt);
    prep_x<<<2048, 256, 0, stream>>>(x, xb);
    gemm8<<<256, 512, 0, stream>>>(xb, Bt, bias, out);
}

// Round 9
// 257.495 us; speedup vs baseline: 1.0882x; 1.0882x over previous
//
#include <hip/hip_runtime.h>

#define M_DIM 2048
#define K_DIM 4096
#define N_DIM 4096
#define KTILES (K_DIM / 64)

typedef unsigned short u16;
typedef unsigned int u32;
typedef __bf16 bf16x8 __attribute__((ext_vector_type(8)));
typedef float f32x4 __attribute__((ext_vector_type(4)));
typedef float f32x16 __attribute__((ext_vector_type(16)));
typedef float f4 __attribute__((ext_vector_type(4)));
typedef u16 u16x8 __attribute__((ext_vector_type(8)));
typedef u32 u32x4 __attribute__((ext_vector_type(4)));

// fp32 -> bf16 round-to-nearest-even
__device__ __forceinline__ u16 f2bf(float f) {
    unsigned int u = __float_as_uint(f);
    u += 0x7fffu + ((u >> 16) & 1u);
    return (u16)(u >> 16);
}

// pack two fp32 -> (bf16(lo) | bf16(hi)<<16), RNE
__device__ __forceinline__ u32 pack2(float lo, float hi) {
    u32 a = __float_as_uint(lo); a += 0x7fffu + ((a >> 16) & 1u);
    u32 b = __float_as_uint(hi); b += 0x7fffu + ((b >> 16) & 1u);
    return (a >> 16) | (b & 0xffff0000u);
}

// async global->LDS, 16B per lane. LDS dest must be wave-uniform base + lane*16.
__device__ __forceinline__ void load16(const void* g, void* l) {
    __builtin_amdgcn_global_load_lds(
        (__attribute__((address_space(1))) const void*)g,
        (__attribute__((address_space(3))) void*)l,
        16, 0, 0);
}

// ------- prep_t: LDS-free transpose, Bt[n][k] = bf16((mask?W:0)[k][n]) ------
__global__ __launch_bounds__(256) void prep_t(const float* __restrict__ W,
                                              const float* __restrict__ Msk,
                                              u16* __restrict__ Bt) {
    const int t = threadIdx.x;
    const int n0 = (blockIdx.x & 31) * 128;         // 32 n-tiles of 128
    const int k0 = (blockIdx.x >> 5) * 64;          // 64 k-tiles of 64
    const int ko = t & 7;                           // k-octet within tile
    const int ng = t >> 3;                          // n-group (4 cols), 0..31

    const float* Wp = W   + (size_t)(k0 + 8 * ko) * N_DIM + n0 + 4 * ng;
    const float* Mp = Msk + (size_t)(k0 + 8 * ko) * N_DIM + n0 + 4 * ng;

    f4 a[8];
#pragma unroll
    for (int j = 0; j < 8; ++j) {
        f4 wv = *(const f4*)(Wp + (size_t)j * N_DIM);
        f4 mv = *(const f4*)(Mp + (size_t)j * N_DIM);
        a[j][0] = mv[0] != 0.f ? wv[0] : 0.f;
        a[j][1] = mv[1] != 0.f ? wv[1] : 0.f;
        a[j][2] = mv[2] != 0.f ? wv[2] : 0.f;
        a[j][3] = mv[3] != 0.f ? wv[3] : 0.f;
    }

    u16* bp = Bt + (size_t)(n0 + 4 * ng) * K_DIM + k0 + 8 * ko;
#pragma unroll
    for (int i = 0; i < 4; ++i) {                   // n within the float4
        u32x4 o;
        o[0] = pack2(a[0][i], a[1][i]);
        o[1] = pack2(a[2][i], a[3][i]);
        o[2] = pack2(a[4][i], a[5][i]);
        o[3] = pack2(a[6][i], a[7][i]);
        *(u32x4*)(bp + (size_t)i * K_DIM) = o;
    }
}

// ------------------- prep_x: x f32 -> bf16, 16 floats/thread ----------------
__global__ __launch_bounds__(256) void prep_x(const float* __restrict__ x,
                                              u16* __restrict__ xb) {
    const int t = threadIdx.x;
    size_t i = ((size_t)blockIdx.x * 256 + t) * 16;
#pragma unroll
    for (int h = 0; h < 2; ++h) {
        f4 v0 = *(const f4*)(x + i + h * 8);
        f4 v1 = *(const f4*)(x + i + h * 8 + 4);
        u16x8 o;
        o[0] = f2bf(v0[0]); o[1] = f2bf(v0[1]); o[2] = f2bf(v0[2]); o[3] = f2bf(v0[3]);
        o[4] = f2bf(v1[0]); o[5] = f2bf(v1[1]); o[6] = f2bf(v1[2]); o[7] = f2bf(v1[3]);
        *(u16x8*)(xb + i + h * 8) = o;
    }
}

// --- gemm8: R6 skeleton (best verified: 65.8us) with 32x32x16 MFMA ----------
// 128m x 256n tile, 2m x 2n x 2k waves, triple-buffer, end-of-iter vmcnt(6)
// (never drains), XCD swizzle, cross-k LDS reduce epilogue — all identical to
// R6. Only the MFMA shape changes: 16 x v_mfma_f32_32x32x16_bf16 per wave per
// K-tile (was 32 x 16x16x32), cutting matrix-pipe cycles ~17% and halving
// MFMA issue slots. ds_read count/order unchanged (A:2mb x 2ks, B0/B1: 2nb x
// 2ks each) so the lgkm(4)/lgkm(0) certification split is 1:1 with R6.
// Input frags: free=lane&31, k-half=lane>>5 (8 contiguous k bf16 per lane).
// C/D: col=lane&31, row=(reg&3)+8*(reg>>2)+4*(lane>>5) [m74/m101 verified].
// Swizzle algebra unchanged: row&7 == lane&7 for both A (mo,mb*32 mult of 32)
// and B rows; 16-lane read groups still 2 lanes/bank -> conflict-free.
__global__ __launch_bounds__(512, 2) void gemm8(const u16* __restrict__ A,   // M x K bf16
                                                const u16* __restrict__ Bt,  // N x K bf16
                                                const float* __restrict__ bias,
                                                float* __restrict__ C) {
    __shared__ __align__(16) u16 As[3][128 * 64];   // 3 x 16 KB
    __shared__ __align__(16) u16 Bs[3][256 * 64];   // 3 x 32 KB

    const int t = threadIdx.x;
    // XCD-aware decode: XCD x owns an 8(bm) x 4(bn) chunk
    const int wgid = blockIdx.x;        // 256 WGs, wgid%8 == XCD [m09]
    const int xcd = wgid & 7, c = wgid >> 3;
    const int bm = (xcd & 1) * 8 + (c & 7);     // M/128 = 16
    const int bn = (xcd >> 1) * 4 + (c >> 3);   // N/256 = 16

    const int srow   = t >> 3;
    const int schunk = (t & 7) ^ (srow & 7);
    const u16* gA = A  + (size_t)(bm * 128 + srow) * K_DIM + schunk * 8;
    const u16* gB = Bt + (size_t)(bn * 256 + srow) * K_DIM + schunk * 8;

    const int lane = t & 63;
    const int wv   = t >> 6;
    const int kh = wv >> 2;             // k-half of every K-tile (0/1)
    const int wq = wv & 3;              // position in 2m x 2n wave grid
    const int mo = (wq >> 1) * 64;      // wave m-origin (0/64)
    const int no = (wq & 1) * 128;      // wave n-origin (0/128)
    const int ln31 = lane & 31;         // 32x32 free-dim index
    const int hi   = lane >> 5;         // k-half-of-16 selector
    const int sw7  = lane & 7;          // row-phase for the XOR swizzle
    // logical k-chunk for mfma k-step ks: kh*4 + ks*2 + hi; phys via XOR
    const int colK0 = ((kh * 4 + 0 + hi) ^ sw7) * 8;   // ks = 0
    const int colK1 = ((kh * 4 + 2 + hi) ^ sw7) * 8;   // ks = 1

#define SA(buf, kt, j) load16(gA + (size_t)(kt) * 64 + (size_t)(j) * 64 * K_DIM, \
                              (buf) + (j) * 4096 + t * 8)
#define SB(buf, kt, j) load16(gB + (size_t)(kt) * 64 + (size_t)(j) * 64 * K_DIM, \
                              (buf) + (j) * 4096 + t * 8)

    f32x16 acc[2][4] = {};   // [mb: m 2x32][nb: n 4x32]

    // rotating buffer pointers (register-held; never runtime-indexed)
    u16 *aC = (u16*)As[0], *aN1 = (u16*)As[1], *aN2 = (u16*)As[2];
    u16 *bC = (u16*)Bs[0], *bN1 = (u16*)Bs[1], *bN2 = (u16*)Bs[2];

    // prologue: stage tiles 0 and 1 (12 loads in flight), certify tile 0
    SA(aC, 0, 0);  SA(aC, 0, 1);
    SB(bC, 0, 0);  SB(bC, 0, 1);  SB(bC, 0, 2);  SB(bC, 0, 3);
    SA(aN1, 1, 0); SA(aN1, 1, 1);
    SB(bN1, 1, 0); SB(bN1, 1, 1); SB(bN1, 1, 2); SB(bN1, 1, 3);
    asm volatile("s_waitcnt vmcnt(6)" ::: "memory");
    __builtin_amdgcn_sched_barrier(0);
    __builtin_amdgcn_s_barrier();

    for (int kt = 0; kt < KTILES; ++kt) {
        const int kn = (kt + 2) & (KTILES - 1);   // wrap loads: harmless re-stage
        bf16x8 fA[2][2], fB0[2][2], fB1[2][2];    // [blk][ks]

        // ---- issue ALL 12 fragment reads for tile kt (order: A, B0, B1) ---
#pragma unroll
        for (int mb = 0; mb < 2; ++mb)
#pragma unroll
            for (int ks = 0; ks < 2; ++ks)
                fA[mb][ks] = *(const bf16x8*)(
                    aC + (mo + mb * 32 + ln31) * 64 + (ks ? colK1 : colK0));
#pragma unroll
        for (int nb = 0; nb < 2; ++nb)
#pragma unroll
            for (int ks = 0; ks < 2; ++ks)
                fB0[nb][ks] = *(const bf16x8*)(
                    bC + (no + nb * 32 + ln31) * 64 + (ks ? colK1 : colK0));
#pragma unroll
        for (int nb = 0; nb < 2; ++nb)
#pragma unroll
            for (int ks = 0; ks < 2; ++ks)
                fB1[nb][ks] = *(const bf16x8*)(
                    bC + (no + 64 + nb * 32 + ln31) * 64 + (ks ? colK1 : colK0));

        // ---- stage A + B-band0 of tile kt+2 (write-after-read safe: all
        //      readers of this buffer lgkm(0)-certified before prev barrier) -
        SA(aN2, kn, 0); SA(aN2, kn, 1); SB(bN2, kn, 0);

        // certify the 8 A/B0 reads (4 B1 reads stay outstanding, DS in-order)
        asm volatile("s_waitcnt lgkmcnt(4)" ::: "memory");
        __builtin_amdgcn_sched_barrier(0);
        __builtin_amdgcn_s_setprio(1);
#pragma unroll
        for (int mb = 0; mb < 2; ++mb)
#pragma unroll
            for (int nb = 0; nb < 2; ++nb)
#pragma unroll
                for (int ks = 0; ks < 2; ++ks)
                    acc[mb][nb] = __builtin_amdgcn_mfma_f32_32x32x16_bf16(
                        fA[mb][ks], fB0[nb][ks], acc[mb][nb], 0, 0, 0);
        __builtin_amdgcn_s_setprio(0);
        // certify B1 (covered by the 8-MFMA cluster above)
        asm volatile("s_waitcnt lgkmcnt(0)" ::: "memory");
        __builtin_amdgcn_sched_barrier(0);
        SB(bN2, kn, 1); SB(bN2, kn, 2); SB(bN2, kn, 3);
        __builtin_amdgcn_s_setprio(1);
#pragma unroll
        for (int mb = 0; mb < 2; ++mb)
#pragma unroll
            for (int nb = 0; nb < 2; ++nb)
#pragma unroll
                for (int ks = 0; ks < 2; ++ks)
                    acc[mb][nb + 2] = __builtin_amdgcn_mfma_f32_32x32x16_bf16(
                        fA[mb][ks], fB1[nb][ks], acc[mb][nb + 2], 0, 0, 0);
        __builtin_amdgcn_s_setprio(0);
        // certify tile kt+1 (oldest 6 of 12 outstanding); never drains to 0
        asm volatile("s_waitcnt vmcnt(6)" ::: "memory");
        __builtin_amdgcn_sched_barrier(0);
        __builtin_amdgcn_s_barrier();

        // rotate buffers: tile T lives in buf[T % 3]
        u16* tmp;
        tmp = aC; aC = aN1; aN1 = aN2; aN2 = tmp;
        tmp = bC; bC = bN1; bN1 = bN2; bN2 = tmp;
    }

    // ---- epilogue: cross-k-half reduction through LDS ----------------------
    asm volatile("s_waitcnt vmcnt(0)" ::: "memory");
    __builtin_amdgcn_s_barrier();

    // 32 KB region per wq: wq 0..2 -> Bs[wq] (32 KB each), wq 3 -> As (48 KB)
    float* red = (wq == 3) ? (float*)As : (float*)Bs[wq];

    if (kh == 1) {
#pragma unroll
        for (int mb = 0; mb < 2; ++mb)
#pragma unroll
            for (int nb = 0; nb < 4; ++nb)
#pragma unroll
                for (int c4 = 0; c4 < 4; ++c4) {
                    f32x4 v = { acc[mb][nb][c4 * 4 + 0], acc[mb][nb][c4 * 4 + 1],
                                acc[mb][nb][c4 * 4 + 2], acc[mb][nb][c4 * 4 + 3] };
                    *(f32x4*)(red + ((mb * 4 + nb) * 4 + c4) * 256 + lane * 4) = v;
                }
    }
    asm volatile("s_waitcnt lgkmcnt(0)" ::: "memory");
    __builtin_amdgcn_s_barrier();

    if (kh == 0) {
#pragma unroll
        for (int mb = 0; mb < 2; ++mb) {
#pragma unroll
            for (int nb = 0; nb < 4; ++nb) {
                const int n = bn * 256 + no + nb * 32 + ln31;
                const float bv = bias[n];
#pragma unroll
                for (int c4 = 0; c4 < 4; ++c4) {
                    f32x4 o4 = *(const f32x4*)(red + ((mb * 4 + nb) * 4 + c4) * 256 + lane * 4);
#pragma unroll
                    for (int w = 0; w < 4; ++w) {
                        // reg r = c4*4+w: row = (r&3) + 8*(r>>2) + 4*hi
                        const int m = bm * 128 + mo + mb * 32 + w + 8 * c4 + 4 * hi;
                        C[(size_t)m * N_DIM + n] = acc[mb][nb][c4 * 4 + w] + o4[w] + bv;
                    }
                }
            }
        }
    }
#undef SA
#undef SB
}

extern "C" void kernel_launch(void* const* d_in, const int* in_sizes, int n_in,
                              void* d_out, int out_size, void* d_ws, size_t ws_size,
                              hipStream_t stream) {
    const float* x    = (const float*)d_in[0];  // 2048 x 4096
    const float* mask = (const float*)d_in[1];  // 4096 x 4096
    const float* W    = (const float*)d_in[2];  // 4096 x 4096
    const float* bias = (const float*)d_in[3];  // 4096
    float* out = (float*)d_out;                 // 2048 x 4096

    u16* Bt = (u16*)d_ws;                                   // N*K bf16 = 32 MB
    u16* xb = (u16*)d_ws + (size_t)N_DIM * K_DIM;           // M*K bf16 = 16 MB

    prep_t<<<2048, 256, 0, stream>>>(W, mask, Bt);
    prep_x<<<2048, 256, 0, stream>>>(x, xb);
    gemm8<<<256, 512, 0, stream>>>(xb, Bt, bias, out);
}

// Round 10
// 242.040 us; speedup vs baseline: 1.1577x; 1.0639x over previous
//
#include <hip/hip_runtime.h>

#define M_DIM 2048
#define K_DIM 4096
#define N_DIM 4096
#define KTILES (K_DIM / 64)

typedef unsigned short u16;
typedef unsigned int u32;
typedef __bf16 bf16x8 __attribute__((ext_vector_type(8)));
typedef float f32x4 __attribute__((ext_vector_type(4)));
typedef float f4 __attribute__((ext_vector_type(4)));
typedef u16 u16x8 __attribute__((ext_vector_type(8)));
typedef u32 u32x4 __attribute__((ext_vector_type(4)));

// fp32 -> bf16 round-to-nearest-even
__device__ __forceinline__ u16 f2bf(float f) {
    unsigned int u = __float_as_uint(f);
    u += 0x7fffu + ((u >> 16) & 1u);
    return (u16)(u >> 16);
}

// pack two fp32 -> (bf16(lo) | bf16(hi)<<16), RNE
__device__ __forceinline__ u32 pack2(float lo, float hi) {
    u32 a = __float_as_uint(lo); a += 0x7fffu + ((a >> 16) & 1u);
    u32 b = __float_as_uint(hi); b += 0x7fffu + ((b >> 16) & 1u);
    return (a >> 16) | (b & 0xffff0000u);
}

// async global->LDS, 16B per lane. LDS dest must be wave-uniform base + lane*16.
__device__ __forceinline__ void load16(const void* g, void* l) {
    __builtin_amdgcn_global_load_lds(
        (__attribute__((address_space(1))) const void*)g,
        (__attribute__((address_space(3))) void*)l,
        16, 0, 0);
}

// --------------- fused prep (R1-verified): LDS-free transpose + x->bf16 -----
// blocks [0, 2048): one 64(k) x 128(n) tile of W/mask -> Bt[n][k] bf16.
// blocks [2048, 4096): convert 4096 contiguous floats of x -> xb (16/thread).
// Fused in ONE dispatch so conv-x blocks backfill CUs during the transpose
// tail and one launch gap is removed.
__global__ __launch_bounds__(256) void prep(const float* __restrict__ x,
                                            u16* __restrict__ xb,
                                            const float* __restrict__ W,
                                            const float* __restrict__ Msk,
                                            u16* __restrict__ Bt) {
    const int t = threadIdx.x;
    if (blockIdx.x >= 2048) {
        // ---- conv_x: 16 floats/thread ----
        size_t i = ((size_t)(blockIdx.x - 2048) * 256 + t) * 16;
#pragma unroll
        for (int h = 0; h < 2; ++h) {
            f4 v0 = *(const f4*)(x + i + h * 8);
            f4 v1 = *(const f4*)(x + i + h * 8 + 4);
            u16x8 o;
            o[0] = f2bf(v0[0]); o[1] = f2bf(v0[1]); o[2] = f2bf(v0[2]); o[3] = f2bf(v0[3]);
            o[4] = f2bf(v1[0]); o[5] = f2bf(v1[1]); o[6] = f2bf(v1[2]); o[7] = f2bf(v1[3]);
            *(u16x8*)(xb + i + h * 8) = o;
        }
        return;
    }
    const int n0 = (blockIdx.x & 31) * 128;         // 32 n-tiles of 128
    const int k0 = (blockIdx.x >> 5) * 64;          // 64 k-tiles of 64
    const int ko = t & 7;                           // k-octet within tile
    const int ng = t >> 3;                          // n-group (4 cols), 0..31

    const float* Wp = W   + (size_t)(k0 + 8 * ko) * N_DIM + n0 + 4 * ng;
    const float* Mp = Msk + (size_t)(k0 + 8 * ko) * N_DIM + n0 + 4 * ng;

    f4 a[8];
#pragma unroll
    for (int j = 0; j < 8; ++j) {
        f4 wv = *(const f4*)(Wp + (size_t)j * N_DIM);
        f4 mv = *(const f4*)(Mp + (size_t)j * N_DIM);
        a[j][0] = mv[0] != 0.f ? wv[0] : 0.f;
        a[j][1] = mv[1] != 0.f ? wv[1] : 0.f;
        a[j][2] = mv[2] != 0.f ? wv[2] : 0.f;
        a[j][3] = mv[3] != 0.f ? wv[3] : 0.f;
    }

    u16* bp = Bt + (size_t)(n0 + 4 * ng) * K_DIM + k0 + 8 * ko;
#pragma unroll
    for (int i = 0; i < 4; ++i) {                   // n within the float4
        u32x4 o;
        o[0] = pack2(a[0][i], a[1][i]);
        o[1] = pack2(a[2][i], a[3][i]);
        o[2] = pack2(a[4][i], a[5][i]);
        o[3] = pack2(a[6][i], a[7][i]);
        *(u32x4*)(bp + (size_t)i * K_DIM) = o;
    }
}

// --- gemm8 (R6-verified, 65.8us / 1045 TF / util 42.6 / conflicts 0) --------
// 128m x 256n tile, 2m x 2n x 2k waves, triple-buffer, 1-barrier covered-wait
// loop, XCD swizzle, cross-k LDS reduce epilogue. Restored VERBATIM after the
// R7 (mid-iteration barrier: exposed vmcnt(0), -13%) and R9 (32x32x16 MFMA:
// inherent 4-way LDS read conflict with 128B rows, -24%) regressions.
__global__ __launch_bounds__(512, 2) void gemm8(const u16* __restrict__ A,   // M x K bf16
                                                const u16* __restrict__ Bt,  // N x K bf16
                                                const float* __restrict__ bias,
                                                float* __restrict__ C) {
    __shared__ __align__(16) u16 As[3][128 * 64];   // 3 x 16 KB
    __shared__ __align__(16) u16 Bs[3][256 * 64];   // 3 x 32 KB

    const int t = threadIdx.x;
    // XCD-aware decode: XCD x owns an 8(bm) x 4(bn) chunk -> 16 MB working set
    const int wgid = blockIdx.x;        // 256 WGs, wgid%8 == XCD [m09]
    const int xcd = wgid & 7, c = wgid >> 3;
    const int bm = (xcd & 1) * 8 + (c & 7);     // M/128 = 16
    const int bn = (xcd >> 1) * 4 + (c >> 3);   // N/256 = 16

    const int srow   = t >> 3;
    const int schunk = (t & 7) ^ (srow & 7);
    const u16* gA = A  + (size_t)(bm * 128 + srow) * K_DIM + schunk * 8;
    const u16* gB = Bt + (size_t)(bn * 256 + srow) * K_DIM + schunk * 8;

    const int lane = t & 63;
    const int wv   = t >> 6;
    const int kh = wv >> 2;             // k-half of every K-tile (0/1)
    const int wq = wv & 3;              // position in 2m x 2n wave grid
    const int mo = (wq >> 1) * 64;      // wave m-origin (0/64)
    const int no = (wq & 1) * 128;      // wave n-origin (0/128)
    const int fr = lane & 15;
    const int q  = lane >> 4;
    const int sw = fr & 7;
    const int colK = (((kh << 2) + q) ^ sw) * 8;

#define SA(buf, kt, j) load16(gA + (size_t)(kt) * 64 + (size_t)(j) * 64 * K_DIM, \
                              (buf) + (j) * 4096 + t * 8)
#define SB(buf, kt, j) load16(gB + (size_t)(kt) * 64 + (size_t)(j) * 64 * K_DIM, \
                              (buf) + (j) * 4096 + t * 8)

    f32x4 acc[4][8] = {};   // [i: m 4x16][j: n 8x16]

    // rotating buffer pointers (register-held; never runtime-indexed)
    u16 *aC = (u16*)As[0], *aN1 = (u16*)As[1], *aN2 = (u16*)As[2];
    u16 *bC = (u16*)Bs[0], *bN1 = (u16*)Bs[1], *bN2 = (u16*)Bs[2];

    // prologue: stage tiles 0 and 1 (12 loads in flight), certify tile 0
    SA(aC, 0, 0);  SA(aC, 0, 1);
    SB(bC, 0, 0);  SB(bC, 0, 1);  SB(bC, 0, 2);  SB(bC, 0, 3);
    SA(aN1, 1, 0); SA(aN1, 1, 1);
    SB(bN1, 1, 0); SB(bN1, 1, 1); SB(bN1, 1, 2); SB(bN1, 1, 3);
    asm volatile("s_waitcnt vmcnt(6)" ::: "memory");
    __builtin_amdgcn_sched_barrier(0);
    __builtin_amdgcn_s_barrier();

    for (int kt = 0; kt < KTILES; ++kt) {
        const int kn = (kt + 2) & (KTILES - 1);   // wrap loads: harmless re-stage
        bf16x8 fA[4], fB0[4], fB1[4];

        // ---- issue ALL fragment reads for tile kt (buffer certified) ------
#pragma unroll
        for (int i = 0; i < 4; ++i)
            fA[i] = *(const bf16x8*)(aC + (mo + i * 16 + fr) * 64 + colK);
#pragma unroll
        for (int j = 0; j < 4; ++j)
            fB0[j] = *(const bf16x8*)(bC + (no + j * 16 + fr) * 64 + colK);
#pragma unroll
        for (int j = 0; j < 4; ++j)
            fB1[j] = *(const bf16x8*)(bC + (no + 64 + j * 16 + fr) * 64 + colK);
        // ---- stage A + B-band0 of tile kt+2 (buf (kt+2)%3: readers done) --
        SA(aN2, kn, 0); SA(aN2, kn, 1); SB(bN2, kn, 0);
        // certify the 8 A/B0 reads (4 B1 reads stay outstanding, DS in-order)
        asm volatile("s_waitcnt lgkmcnt(4)" ::: "memory");
        __builtin_amdgcn_sched_barrier(0);
        __builtin_amdgcn_s_setprio(1);
#pragma unroll
        for (int i = 0; i < 4; ++i)
#pragma unroll
            for (int j = 0; j < 4; ++j)
                acc[i][j] = __builtin_amdgcn_mfma_f32_16x16x32_bf16(
                    fA[i], fB0[j], acc[i][j], 0, 0, 0);
        __builtin_amdgcn_s_setprio(0);
        // certify B1 (covered by the 16-MFMA cluster above)
        asm volatile("s_waitcnt lgkmcnt(0)" ::: "memory");
        __builtin_amdgcn_sched_barrier(0);
        SB(bN2, kn, 1); SB(bN2, kn, 2); SB(bN2, kn, 3);
        __builtin_amdgcn_s_setprio(1);
#pragma unroll
        for (int i = 0; i < 4; ++i)
#pragma unroll
            for (int j = 0; j < 4; ++j)
                acc[i][j + 4] = __builtin_amdgcn_mfma_f32_16x16x32_bf16(
                    fA[i], fB1[j], acc[i][j + 4], 0, 0, 0);
        __builtin_amdgcn_s_setprio(0);
        // certify tile kt+1 (oldest 6 of 12 outstanding); never drains to 0
        asm volatile("s_waitcnt vmcnt(6)" ::: "memory");
        __builtin_amdgcn_sched_barrier(0);
        __builtin_amdgcn_s_barrier();

        // rotate buffers: tile T lives in buf[T % 3]
        u16* tmp;
        tmp = aC; aC = aN1; aN1 = aN2; aN2 = tmp;
        tmp = bC; bC = bN1; bN1 = bN2; bN2 = tmp;
    }

    // ---- epilogue: cross-k-half reduction through LDS ----------------------
    asm volatile("s_waitcnt vmcnt(0)" ::: "memory");
    __builtin_amdgcn_s_barrier();

    // 32 KB region per wq: wq 0..2 -> Bs[wq] (32 KB each), wq 3 -> As (48 KB)
    float* red = (wq == 3) ? (float*)As : (float*)Bs[wq];

    if (kh == 1) {
#pragma unroll
        for (int i = 0; i < 4; ++i)
#pragma unroll
            for (int j = 0; j < 8; ++j)
                *(f32x4*)(red + (i * 8 + j) * 256 + lane * 4) = acc[i][j];
    }
    asm volatile("s_waitcnt lgkmcnt(0)" ::: "memory");
    __builtin_amdgcn_s_barrier();

    if (kh == 0) {
        const int rb = q * 4;
#pragma unroll
        for (int i = 0; i < 4; ++i) {
#pragma unroll
            for (int j = 0; j < 8; ++j) {
                f32x4 other = *(const f32x4*)(red + (i * 8 + j) * 256 + lane * 4);
                int n = bn * 256 + no + j * 16 + fr;
                float bv = bias[n];
#pragma unroll
                for (int r = 0; r < 4; ++r) {
                    int m = bm * 128 + mo + i * 16 + rb + r;
                    C[(size_t)m * N_DIM + n] = acc[i][j][r] + other[r] + bv;
                }
            }
        }
    }
#undef SA
#undef SB
}

extern "C" void kernel_launch(void* const* d_in, const int* in_sizes, int n_in,
                              void* d_out, int out_size, void* d_ws, size_t ws_size,
                              hipStream_t stream) {
    const float* x    = (const float*)d_in[0];  // 2048 x 4096
    const float* mask = (const float*)d_in[1];  // 4096 x 4096
    const float* W    = (const float*)d_in[2];  // 4096 x 4096
    const float* bias = (const float*)d_in[3];  // 4096
    float* out = (float*)d_out;                 // 2048 x 4096

    u16* Bt = (u16*)d_ws;                                   // N*K bf16 = 32 MB
    u16* xb = (u16*)d_ws + (size_t)N_DIM * K_DIM;           // M*K bf16 = 16 MB

    // prep signature is (x, xb, W, Msk, Bt) — keep argument order exact.
    prep<<<4096, 256, 0, stream>>>(x, xb, W, mask, Bt);
    gemm8<<<256, 512, 0, stream>>>(xb, Bt, bias, out);
}

// Round 11
// 238.037 us; speedup vs baseline: 1.1771x; 1.0168x over previous
//
#include <hip/hip_runtime.h>

#define M_DIM 2048
#define K_DIM 4096
#define N_DIM 4096
#define KTILES (K_DIM / 64)

typedef unsigned short u16;
typedef unsigned int u32;
typedef __bf16 bf16x8 __attribute__((ext_vector_type(8)));
typedef float f32x4 __attribute__((ext_vector_type(4)));
typedef float f4 __attribute__((ext_vector_type(4)));
typedef u16 u16x8 __attribute__((ext_vector_type(8)));
typedef u32 u32x4 __attribute__((ext_vector_type(4)));

// fp32 -> bf16 round-to-nearest-even
__device__ __forceinline__ u16 f2bf(float f) {
    unsigned int u = __float_as_uint(f);
    u += 0x7fffu + ((u >> 16) & 1u);
    return (u16)(u >> 16);
}

// pack two fp32 -> (bf16(lo) | bf16(hi)<<16), RNE
__device__ __forceinline__ u32 pack2(float lo, float hi) {
    u32 a = __float_as_uint(lo); a += 0x7fffu + ((a >> 16) & 1u);
    u32 b = __float_as_uint(hi); b += 0x7fffu + ((b >> 16) & 1u);
    return (a >> 16) | (b & 0xffff0000u);
}

// async global->LDS, 16B per lane. LDS dest must be wave-uniform base + lane*16.
__device__ __forceinline__ void load16(const void* g, void* l) {
    __builtin_amdgcn_global_load_lds(
        (__attribute__((address_space(1))) const void*)g,
        (__attribute__((address_space(3))) void*)l,
        16, 0, 0);
}

// --------------- fused prep v3: wave-contiguous reads + LDS transpose -------
// blocks [0, 1024): one 64(k) x 256(n) tile of W/mask -> Bt[n][k] bf16.
//   Phase 1: per wave-instr read ONE FULL 1KB row of W (and mask) — fully
//   contiguous per instruction (the old intra-thread-transpose made adjacent
//   lanes 16KB apart: 8x128B scatter per instr -> measured 25% HBM, 68us).
//   Masked f32 goes to a 64KB LDS tile with float4-chunk swizzle
//   c' = c ^ (k>>3): write instrs are const-XOR (inherent cost only), and
//   column reads get the k-octet into bank bits 2-4 -> 2 lanes/bank (free).
//   Phase 2: thread (oct=t&7, nn=t>>3) packs k-pairs (f32->bf16) and stores
//   one uint4 per n; 8 lanes form 128B-contiguous Bt segments (only 8
//   scattered instrs/thread remain, on the 32MB write side).
// blocks [1024, 3072): convert 4096 contiguous floats of x -> xb (16/thread).
__global__ __launch_bounds__(256) void prep(const float* __restrict__ x,
                                            u16* __restrict__ xb,
                                            const float* __restrict__ W,
                                            const float* __restrict__ Msk,
                                            u16* __restrict__ Bt) {
    const int t = threadIdx.x;
    if (blockIdx.x >= 1024) {
        // ---- conv_x: 16 floats/thread ----
        size_t i = ((size_t)(blockIdx.x - 1024) * 256 + t) * 16;
#pragma unroll
        for (int h = 0; h < 2; ++h) {
            f4 v0 = *(const f4*)(x + i + h * 8);
            f4 v1 = *(const f4*)(x + i + h * 8 + 4);
            u16x8 o;
            o[0] = f2bf(v0[0]); o[1] = f2bf(v0[1]); o[2] = f2bf(v0[2]); o[3] = f2bf(v0[3]);
            o[4] = f2bf(v1[0]); o[5] = f2bf(v1[1]); o[6] = f2bf(v1[2]); o[7] = f2bf(v1[3]);
            *(u16x8*)(xb + i + h * 8) = o;
        }
        return;
    }
    __shared__ __align__(16) float S[64 * 256];     // 64 KB masked-f32 tile

    const int k0 = (blockIdx.x >> 4) * 64;          // 64 k-tiles of 64
    const int n0 = (blockIdx.x & 15) * 256;         // 16 n-tiles of 256
    const int w = t >> 6;                           // wave 0..3
    const int l = t & 63;                           // lane

    // ---- phase 1: row-contiguous reads; swizzled float4 writes to LDS -----
    // (j, w) -> row k = 4j + w; lane l -> float4-chunk c = l (4 cols).
#pragma unroll
    for (int j = 0; j < 16; ++j) {
        const int k = 4 * j + w;
        const size_t g = (size_t)(k0 + k) * N_DIM + n0 + 4 * l;
        f4 wv = *(const f4*)(W + g);
        f4 mv = *(const f4*)(Msk + g);
        f4 o;
        o[0] = mv[0] != 0.f ? wv[0] : 0.f;
        o[1] = mv[1] != 0.f ? wv[1] : 0.f;
        o[2] = mv[2] != 0.f ? wv[2] : 0.f;
        o[3] = mv[3] != 0.f ? wv[3] : 0.f;
        // swizzled chunk: c' = l ^ (k>>3); 16B-aligned b128 write
        *(f4*)(S + k * 256 + ((l ^ (k >> 3)) << 2)) = o;
    }
    __syncthreads();

    // ---- phase 2: column reads (2 lanes/bank), pack k-pairs, store --------
    const int oct = t & 7;                          // k-octet 0..7
    const int nn  = t >> 3;                         // 0..31
#pragma unroll
    for (int i = 0; i < 8; ++i) {
        const int nl = nn + 32 * i;                 // tile-local n 0..255
        float f[8];
#pragma unroll
        for (int j = 0; j < 8; ++j) {
            const int k = 8 * oct + j;              // k>>3 == oct
            f[j] = S[k * 256 + (((nl >> 2) ^ oct) << 2) + (nl & 3)];
        }
        u32x4 o;
        o[0] = pack2(f[0], f[1]);
        o[1] = pack2(f[2], f[3]);
        o[2] = pack2(f[4], f[5]);
        o[3] = pack2(f[6], f[7]);
        *(u32x4*)(Bt + (size_t)(n0 + nl) * K_DIM + k0 + oct * 8) = o;
    }
}

// --- gemm8 (R6-verified, 65.8us / 1045 TF / util 42.6 / conflicts 0) --------
// 128m x 256n tile, 2m x 2n x 2k waves, triple-buffer, 1-barrier covered-wait
// loop, XCD swizzle, cross-k LDS reduce epilogue. VERBATIM — do not touch.
__global__ __launch_bounds__(512, 2) void gemm8(const u16* __restrict__ A,   // M x K bf16
                                                const u16* __restrict__ Bt,  // N x K bf16
                                                const float* __restrict__ bias,
                                                float* __restrict__ C) {
    __shared__ __align__(16) u16 As[3][128 * 64];   // 3 x 16 KB
    __shared__ __align__(16) u16 Bs[3][256 * 64];   // 3 x 32 KB

    const int t = threadIdx.x;
    // XCD-aware decode: XCD x owns an 8(bm) x 4(bn) chunk -> 16 MB working set
    const int wgid = blockIdx.x;        // 256 WGs, wgid%8 == XCD [m09]
    const int xcd = wgid & 7, c = wgid >> 3;
    const int bm = (xcd & 1) * 8 + (c & 7);     // M/128 = 16
    const int bn = (xcd >> 1) * 4 + (c >> 3);   // N/256 = 16

    const int srow   = t >> 3;
    const int schunk = (t & 7) ^ (srow & 7);
    const u16* gA = A  + (size_t)(bm * 128 + srow) * K_DIM + schunk * 8;
    const u16* gB = Bt + (size_t)(bn * 256 + srow) * K_DIM + schunk * 8;

    const int lane = t & 63;
    const int wv   = t >> 6;
    const int kh = wv >> 2;             // k-half of every K-tile (0/1)
    const int wq = wv & 3;              // position in 2m x 2n wave grid
    const int mo = (wq >> 1) * 64;      // wave m-origin (0/64)
    const int no = (wq & 1) * 128;      // wave n-origin (0/128)
    const int fr = lane & 15;
    const int q  = lane >> 4;
    const int sw = fr & 7;
    const int colK = (((kh << 2) + q) ^ sw) * 8;

#define SA(buf, kt, j) load16(gA + (size_t)(kt) * 64 + (size_t)(j) * 64 * K_DIM, \
                              (buf) + (j) * 4096 + t * 8)
#define SB(buf, kt, j) load16(gB + (size_t)(kt) * 64 + (size_t)(j) * 64 * K_DIM, \
                              (buf) + (j) * 4096 + t * 8)

    f32x4 acc[4][8] = {};   // [i: m 4x16][j: n 8x16]

    // rotating buffer pointers (register-held; never runtime-indexed)
    u16 *aC = (u16*)As[0], *aN1 = (u16*)As[1], *aN2 = (u16*)As[2];
    u16 *bC = (u16*)Bs[0], *bN1 = (u16*)Bs[1], *bN2 = (u16*)Bs[2];

    // prologue: stage tiles 0 and 1 (12 loads in flight), certify tile 0
    SA(aC, 0, 0);  SA(aC, 0, 1);
    SB(bC, 0, 0);  SB(bC, 0, 1);  SB(bC, 0, 2);  SB(bC, 0, 3);
    SA(aN1, 1, 0); SA(aN1, 1, 1);
    SB(bN1, 1, 0); SB(bN1, 1, 1); SB(bN1, 1, 2); SB(bN1, 1, 3);
    asm volatile("s_waitcnt vmcnt(6)" ::: "memory");
    __builtin_amdgcn_sched_barrier(0);
    __builtin_amdgcn_s_barrier();

    for (int kt = 0; kt < KTILES; ++kt) {
        const int kn = (kt + 2) & (KTILES - 1);   // wrap loads: harmless re-stage
        bf16x8 fA[4], fB0[4], fB1[4];

        // ---- issue ALL fragment reads for tile kt (buffer certified) ------
#pragma unroll
        for (int i = 0; i < 4; ++i)
            fA[i] = *(const bf16x8*)(aC + (mo + i * 16 + fr) * 64 + colK);
#pragma unroll
        for (int j = 0; j < 4; ++j)
            fB0[j] = *(const bf16x8*)(bC + (no + j * 16 + fr) * 64 + colK);
#pragma unroll
        for (int j = 0; j < 4; ++j)
            fB1[j] = *(const bf16x8*)(bC + (no + 64 + j * 16 + fr) * 64 + colK);
        // ---- stage A + B-band0 of tile kt+2 (buf (kt+2)%3: readers done) --
        SA(aN2, kn, 0); SA(aN2, kn, 1); SB(bN2, kn, 0);
        // certify the 8 A/B0 reads (4 B1 reads stay outstanding, DS in-order)
        asm volatile("s_waitcnt lgkmcnt(4)" ::: "memory");
        __builtin_amdgcn_sched_barrier(0);
        __builtin_amdgcn_s_setprio(1);
#pragma unroll
        for (int i = 0; i < 4; ++i)
#pragma unroll
            for (int j = 0; j < 4; ++j)
                acc[i][j] = __builtin_amdgcn_mfma_f32_16x16x32_bf16(
                    fA[i], fB0[j], acc[i][j], 0, 0, 0);
        __builtin_amdgcn_s_setprio(0);
        // certify B1 (covered by the 16-MFMA cluster above)
        asm volatile("s_waitcnt lgkmcnt(0)" ::: "memory");
        __builtin_amdgcn_sched_barrier(0);
        SB(bN2, kn, 1); SB(bN2, kn, 2); SB(bN2, kn, 3);
        __builtin_amdgcn_s_setprio(1);
#pragma unroll
        for (int i = 0; i < 4; ++i)
#pragma unroll
            for (int j = 0; j < 4; ++j)
                acc[i][j + 4] = __builtin_amdgcn_mfma_f32_16x16x32_bf16(
                    fA[i], fB1[j], acc[i][j + 4], 0, 0, 0);
        __builtin_amdgcn_s_setprio(0);
        // certify tile kt+1 (oldest 6 of 12 outstanding); never drains to 0
        asm volatile("s_waitcnt vmcnt(6)" ::: "memory");
        __builtin_amdgcn_sched_barrier(0);
        __builtin_amdgcn_s_barrier();

        // rotate buffers: tile T lives in buf[T % 3]
        u16* tmp;
        tmp = aC; aC = aN1; aN1 = aN2; aN2 = tmp;
        tmp = bC; bC = bN1; bN1 = bN2; bN2 = tmp;
    }

    // ---- epilogue: cross-k-half reduction through LDS ----------------------
    asm volatile("s_waitcnt vmcnt(0)" ::: "memory");
    __builtin_amdgcn_s_barrier();

    // 32 KB region per wq: wq 0..2 -> Bs[wq] (32 KB each), wq 3 -> As (48 KB)
    float* red = (wq == 3) ? (float*)As : (float*)Bs[wq];

    if (kh == 1) {
#pragma unroll
        for (int i = 0; i < 4; ++i)
#pragma unroll
            for (int j = 0; j < 8; ++j)
                *(f32x4*)(red + (i * 8 + j) * 256 + lane * 4) = acc[i][j];
    }
    asm volatile("s_waitcnt lgkmcnt(0)" ::: "memory");
    __builtin_amdgcn_s_barrier();

    if (kh == 0) {
        const int rb = q * 4;
#pragma unroll
        for (int i = 0; i < 4; ++i) {
#pragma unroll
            for (int j = 0; j < 8; ++j) {
                f32x4 other = *(const f32x4*)(red + (i * 8 + j) * 256 + lane * 4);
                int n = bn * 256 + no + j * 16 + fr;
                float bv = bias[n];
#pragma unroll
                for (int r = 0; r < 4; ++r) {
                    int m = bm * 128 + mo + i * 16 + rb + r;
                    C[(size_t)m * N_DIM + n] = acc[i][j][r] + other[r] + bv;
                }
            }
        }
    }
#undef SA
#undef SB
}

extern "C" void kernel_launch(void* const* d_in, const int* in_sizes, int n_in,
                              void* d_out, int out_size, void* d_ws, size_t ws_size,
                              hipStream_t stream) {
    const float* x    = (const float*)d_in[0];  // 2048 x 4096
    const float* mask = (const float*)d_in[1];  // 4096 x 4096
    const float* W    = (const float*)d_in[2];  // 4096 x 4096
    const float* bias = (const float*)d_in[3];  // 4096
    float* out = (float*)d_out;                 // 2048 x 4096

    u16* Bt = (u16*)d_ws;                                   // N*K bf16 = 32 MB
    u16* xb = (u16*)d_ws + (size_t)N_DIM * K_DIM;           // M*K bf16 = 16 MB

    // prep: blocks [0,1024) transpose, [1024,3072) x-convert
    prep<<<3072, 256, 0, stream>>>(x, xb, W, mask, Bt);
    gemm8<<<256, 512, 0, stream>>>(xb, Bt, bias, out);
}